// Round 4
// baseline (540.522 us; speedup 1.0000x reference)
//
#include <hip/hip_runtime.h>
#include <hip/hip_bf16.h>
#include <stdint.h>

// HierarchicalGRU on MI355X. B=16384, IN=4096, H=128, NOPT=64.
// Round 8: kill the 4x cache-line amplification on strided weight-fragment
// loads (16B/lane at 8KB stride = 16B used per 64B line).
//  - k_attn: proper dbuf GEMM: B(WaT) staged via global_load_lds (coalesced,
//    1x fetch), pre-swizzled global source + swizzled ds_read (rule #21);
//    A(obs) reg-staged fp32->bf16 into swizzled LDS. One barrier per K-step.
//  - k_gru: separate kernel, 64-row blocks (256 vs 1024 weight re-reads).
//  - ~320us of dur_us is harness 1GB workspace-poison fills (uncontrollable).

typedef __attribute__((ext_vector_type(8))) short bf16x8;
typedef __attribute__((ext_vector_type(4))) float f32x4;
typedef __attribute__((ext_vector_type(8))) float f32x8;

#define INDIM 4096
#define H 128
#define NOPT 64

// workspace layout (uint16 element offsets), bf16 contents
#define WS_WAT    0u        // [128, 4096]
#define WS_WIH0T  524288u   // [384, 128]
#define WS_WHH0T  573440u   // [384, 128]
#define WS_WIH1T  622592u   // [384, 256]
#define WS_WHH1T  720896u   // [384, 128]
#define WS_WV0T   770048u   // [64, 128]
#define WS_WV1T   778240u   // [64, 128]
#define WS_WT0T   786432u   // [64, 128]
#define WS_ATTN   794624u   // [16384, 128] bf16

// output layout (fp32 element offsets)
#define OUT_V0    0u
#define OUT_TERMP 1048576u
#define OUT_V1    1064960u
#define OUT_H0N   2113536u
#define OUT_H1N   4210688u

typedef __attribute__((address_space(1))) const void gas_t;
typedef __attribute__((address_space(3))) void las_t;
static __device__ __forceinline__ void gll16(const void* g, void* l) {
  __builtin_amdgcn_global_load_lds((gas_t*)g, (las_t*)l, 16, 0, 0);
}

static __device__ __forceinline__ uint16_t f2bf(float f) {
  __hip_bfloat16 h = __float2bfloat16(f);
  return __builtin_bit_cast(uint16_t, h);
}
static __device__ __forceinline__ float sigm(float x) { return 1.0f / (1.0f + __expf(-x)); }
static __device__ __forceinline__ float fast_tanh(float x) {
  float e = __expf(2.0f * x);
  return 1.0f - 2.0f / (e + 1.0f);
}
static __device__ __forceinline__ f32x4 mfma16(bf16x8 a, bf16x8 b, f32x4 c) {
  return __builtin_amdgcn_mfma_f32_16x16x32_bf16(a, b, c, 0, 0, 0);
}
static __device__ __forceinline__ bf16x8 cvt8(f32x8 v) {
  bf16x8 r;
#pragma unroll
  for (int j = 0; j < 8; ++j) r[j] = (short)f2bf(v[j]);
  return r;
}

// ---------------- K0: weight transpose+convert  W[K,N] fp32 -> WT[N,K] bf16 ----------------
__global__ void k_transpose(const float* __restrict__ Wa,
                            const float* __restrict__ Wih0,
                            const float* __restrict__ Whh0,
                            const float* __restrict__ Wih1,
                            const float* __restrict__ Whh1,
                            const float* __restrict__ Wv0,
                            const float* __restrict__ Wv1,
                            const float* __restrict__ Wt0,
                            uint16_t* __restrict__ ws) {
  __shared__ float sT[32][34];
  int blk = blockIdx.x;
  const float* in; uint16_t* out; int K; int N; int base;
  if (blk < 512)      { in = Wa;   out = ws + WS_WAT;   K = 4096; N = 128; base = 0; }
  else if (blk < 560) { in = Wih0; out = ws + WS_WIH0T; K = 128;  N = 384; base = 512; }
  else if (blk < 608) { in = Whh0; out = ws + WS_WHH0T; K = 128;  N = 384; base = 560; }
  else if (blk < 704) { in = Wih1; out = ws + WS_WIH1T; K = 256;  N = 384; base = 608; }
  else if (blk < 752) { in = Whh1; out = ws + WS_WHH1T; K = 128;  N = 384; base = 704; }
  else if (blk < 760) { in = Wv0;  out = ws + WS_WV0T;  K = 128;  N = 64;  base = 752; }
  else if (blk < 768) { in = Wv1;  out = ws + WS_WV1T;  K = 128;  N = 64;  base = 760; }
  else                { in = Wt0;  out = ws + WS_WT0T;  K = 128;  N = 64;  base = 768; }
  const int tix = blk - base;
  const int nTK = K >> 5;
  const int kt = tix & (nTK - 1);
  const int nt = tix / nTK;
  const int k0 = kt * 32, n0 = nt * 32;
  const int t = threadIdx.x;
#pragma unroll
  for (int i = 0; i < 4; ++i) {
    int e = i * 256 + t, kk = e >> 5, nn = e & 31;
    sT[kk][nn] = in[(size_t)(k0 + kk) * N + n0 + nn];
  }
  __syncthreads();
#pragma unroll
  for (int i = 0; i < 4; ++i) {
    int e = i * 256 + t, nn = e >> 5, kk = e & 31;
    out[(size_t)(n0 + nn) * K + k0 + kk] = f2bf(sT[kk][nn]);
  }
}

// ---------------- K1: attn = tanh(obs @ WaT^T + ba) ----------------
// 512 blocks x 256 thr (4 waves: wm=w>>1 rows, wn=w&1 col-half). M=32, BK=64.
// A: reg-staged fp32->bf16, XOR-swizzled LDS.  B: global_load_lds, linear LDS
// dest + pre-swizzled global source, swizzled ds_read (same involution).
__launch_bounds__(256, 4)
__global__ void k_attn(const float* __restrict__ obs,
                       uint16_t* __restrict__ ws,
                       const float* __restrict__ ba) {
  __shared__ __align__(16) uint16_t sA[2][32 * 8 * 8];    // [buf][(r*8+physg)*8]
  __shared__ __align__(16) uint16_t sB[2][128 * 8 * 8];   // [buf][(n*8+physg)*8]
  const uint16_t* WaT = ws + WS_WAT;
  uint16_t* attn = ws + WS_ATTN;
  const int t = threadIdx.x, w = t >> 6, lane = t & 63;
  const int l15 = lane & 15, quad = lane >> 4;
  const int wm = w >> 1, wn = w & 1;
  const int row0 = blockIdx.x * 32;
  const int rA = wm * 16 + l15;
  // A staging: thread t -> row sr, 8-elem granule sg of BK=64
  const int sr = t >> 3, sg = t & 7;
  const float* aSrc = obs + (size_t)(row0 + sr) * INDIM + sg * 8;
  const int aDst = (sr * 8 + (sg ^ (sr & 7))) * 8;
  // B staging (gll): inst j of wave w writes LDS granules (w*4+j)*64 + lane.
  // physical granule gph = lane&7 at row n = w*32 + j*8 + (lane>>3);
  // source granule = gph ^ (n&7)  (j*8 doesn't change n&7).
  const int n0 = w * 32 + (lane >> 3);
  const int gsrc = (lane & 7) ^ (n0 & 7);
  const uint16_t* bSrc = WaT + (size_t)n0 * INDIM + gsrc * 8;

  f32x4 acc[4] = {};

  auto compute = [&](int buf) {
#pragma unroll
    for (int ks = 0; ks < 2; ++ks) {
      bf16x8 a = *(const bf16x8*)&sA[buf][(rA * 8 + ((ks * 4 + quad) ^ (rA & 7))) * 8];
#pragma unroll
      for (int nb = 0; nb < 4; ++nb) {
        const int n = wn * 64 + nb * 16 + l15;
        bf16x8 b = *(const bf16x8*)&sB[buf][(n * 8 + ((ks * 4 + quad) ^ (n & 7))) * 8];
        acc[nb] = mfma16(a, b, acc[nb]);
      }
    }
  };

  // prologue: stage tile 0 into buf 0
  {
    f32x8 av = *(const f32x8*)aSrc;
#pragma unroll
    for (int j = 0; j < 4; ++j)
      gll16(bSrc + (size_t)j * 8 * INDIM, (void*)&sB[0][(w * 4 + j) * 512]);
    *(bf16x8*)&sA[0][aDst] = cvt8(av);
  }
  __syncthreads();   // drains vmcnt (gll) + lgkmcnt

  for (int kt = 0; kt < 63; ++kt) {
    const int cur = kt & 1, nxt = cur ^ 1;
    // issue next tile's loads; they fly during compute
    f32x8 av = *(const f32x8*)(aSrc + (size_t)(kt + 1) * 64);
#pragma unroll
    for (int j = 0; j < 4; ++j)
      gll16(bSrc + (size_t)(kt + 1) * 64 + (size_t)j * 8 * INDIM,
            (void*)&sB[nxt][(w * 4 + j) * 512]);
    compute(cur);
    *(bf16x8*)&sA[nxt][aDst] = cvt8(av);
    __syncthreads();
  }
  compute(1);   // tile 63 lives in buf 1

  // epilogue: tanh + bias -> attn (bf16) in ws
#pragma unroll
  for (int nb = 0; nb < 4; ++nb) {
    const int col = wn * 64 + nb * 16 + l15;
    const float bav = ba[col];
#pragma unroll
    for (int i = 0; i < 4; ++i) {
      const int r = wm * 16 + quad * 4 + i;
      attn[(size_t)(row0 + r) * H + col] = f2bf(fast_tanh(acc[nb][i] + bav));
    }
  }
}

// ---------------- K2: GRU0 + heads + GRU1 ----------------
// 256 blocks x 512 thr (8 waves: wm=w>>1 row-group, wn=w&1 gate-col-half).
// Block owns 64 rows -> weight slices re-read 256x (was 1024x).
__launch_bounds__(512, 4)
__global__ void k_gru(const uint16_t* __restrict__ ws,
                      const float* __restrict__ h0,
                      const float* __restrict__ bih0,
                      const float* __restrict__ bhh0,
                      const float* __restrict__ bv0,
                      const float* __restrict__ bt0,
                      const int* __restrict__ chosen,
                      const float* __restrict__ h1,
                      const float* __restrict__ bih1,
                      const float* __restrict__ bhh1,
                      const float* __restrict__ bv1,
                      float* __restrict__ out) {
  __shared__ __align__(16) uint16_t sC[64 * 16 * 8];   // hc tile, swizzled; 16 KB
  const uint16_t* attn  = ws + WS_ATTN;
  const uint16_t* Wih0T = ws + WS_WIH0T;
  const uint16_t* Whh0T = ws + WS_WHH0T;
  const uint16_t* Wih1T = ws + WS_WIH1T;
  const uint16_t* Whh1T = ws + WS_WHH1T;
  const uint16_t* Wv0T  = ws + WS_WV0T;
  const uint16_t* Wv1T  = ws + WS_WV1T;
  const uint16_t* Wt0T  = ws + WS_WT0T;
  const int t = threadIdx.x, w = t >> 6, lane = t & 63;
  const int l15 = lane & 15, quad = lane >> 4;
  const int wm = w >> 1, wn = w & 1;
  const int row0 = blockIdx.x * 64;
  const int rA = wm * 16 + l15;

  // A-frags: attn (bf16, from ws) + h0 (fp32 -> bf16)
  bf16x8 ax[4], ah[4];
#pragma unroll
  for (int ks = 0; ks < 4; ++ks) {
    ax[ks] = *(const bf16x8*)(attn + (size_t)(row0 + rA) * H + ks * 32 + quad * 8);
    ah[ks] = cvt8(*(const f32x8*)(h0 + (size_t)(row0 + rA) * H + ks * 32 + quad * 8));
  }

  // ---- Phase B: GRU layer 0, wave covers gate cols [64wn, 64wn+64) ----
#pragma unroll
  for (int nbl = 0; nbl < 4; ++nbl) {
    const int nb = wn * 4 + nbl;
    const int nrow = nb * 16 + l15;
    f32x4 air = {}, ahr = {}, aiz = {}, ahz = {}, ain = {}, ahn = {};
#pragma unroll
    for (int ks = 0; ks < 4; ++ks) {
      const int k = ks * 32 + quad * 8;
      bf16x8 b;
      b = *(const bf16x8*)(Wih0T + (size_t)(nrow      ) * H + k); air = mfma16(ax[ks], b, air);
      b = *(const bf16x8*)(Wih0T + (size_t)(nrow + 128) * H + k); aiz = mfma16(ax[ks], b, aiz);
      b = *(const bf16x8*)(Wih0T + (size_t)(nrow + 256) * H + k); ain = mfma16(ax[ks], b, ain);
      b = *(const bf16x8*)(Whh0T + (size_t)(nrow      ) * H + k); ahr = mfma16(ah[ks], b, ahr);
      b = *(const bf16x8*)(Whh0T + (size_t)(nrow + 128) * H + k); ahz = mfma16(ah[ks], b, ahz);
      b = *(const bf16x8*)(Whh0T + (size_t)(nrow + 256) * H + k); ahn = mfma16(ah[ks], b, ahn);
    }
    const int col = nrow;
    const float b_ir = bih0[col],       b_hr = bhh0[col];
    const float b_iz = bih0[col + 128], b_hz = bhh0[col + 128];
    const float b_in = bih0[col + 256], b_hn = bhh0[col + 256];
    const int kb = col >> 3;
#pragma unroll
    for (int i = 0; i < 4; ++i) {
      const int r = wm * 16 + quad * 4 + i;
      const int grow = row0 + r;
      const float rr = sigm(air[i] + ahr[i] + b_ir + b_hr);
      const float zz = sigm(aiz[i] + ahz[i] + b_iz + b_hz);
      const float nn = fast_tanh(ain[i] + b_in + rr * (ahn[i] + b_hn));
      const float hv = h0[(size_t)grow * H + col];
      const float hnew = (1.0f - zz) * nn + zz * hv;
      out[OUT_H0N + (size_t)grow * H + col] = hnew;
      sC[(r * 16 + (kb ^ (r & 7))) * 8 + (col & 7)] = f2bf(0.5f * hnew + 0.25f);
    }
  }
  __syncthreads();   // sC (hc0) complete

  // ---- Heads 0: v0 + term. Wave covers col-frags {2wn, 2wn+1} for its rows ----
  {
    bf16x8 ac[4];
#pragma unroll
    for (int ks = 0; ks < 4; ++ks)
      ac[ks] = *(const bf16x8*)&sC[(rA * 16 + ((ks * 4 + quad) ^ (rA & 7))) * 8];
    int ch[4];
#pragma unroll
    for (int i = 0; i < 4; ++i) ch[i] = chosen[row0 + wm * 16 + quad * 4 + i];
#pragma unroll
    for (int hb = 0; hb < 2; ++hb) {
      const int colf = wn * 2 + hb;
      const int nrow = colf * 16 + l15;
      f32x4 av = {}, at = {};
#pragma unroll
      for (int ks = 0; ks < 4; ++ks) {
        const int k = ks * 32 + quad * 8;
        bf16x8 b;
        b = *(const bf16x8*)(Wv0T + (size_t)nrow * H + k); av = mfma16(ac[ks], b, av);
        b = *(const bf16x8*)(Wt0T + (size_t)nrow * H + k); at = mfma16(ac[ks], b, at);
      }
      const int col = nrow;
      const float bvv = bv0[col], btv = bt0[col];
#pragma unroll
      for (int i = 0; i < 4; ++i) {
        const int grow = row0 + wm * 16 + quad * 4 + i;
        out[OUT_V0 + (size_t)grow * NOPT + col] = av[i] + bvv;
        if (ch[i] == col)
          out[OUT_TERMP + grow] = sigm(at[i] + btv);
      }
    }
  }
  __syncthreads();   // heads-0 reads done; sC reusable

  // ---- Phase C: GRU layer 1 (x1 = [attn | h1]) ----
  bf16x8 ah1[4];
#pragma unroll
  for (int ks = 0; ks < 4; ++ks)
    ah1[ks] = cvt8(*(const f32x8*)(h1 + (size_t)(row0 + rA) * H + ks * 32 + quad * 8));
#pragma unroll
  for (int nbl = 0; nbl < 4; ++nbl) {
    const int nb = wn * 4 + nbl;
    const int nrow = nb * 16 + l15;
    f32x4 air = {}, ahr = {}, aiz = {}, ahz = {}, ain = {}, ahn = {};
#pragma unroll
    for (int ks = 0; ks < 8; ++ks) {   // gi1 over K=256
      const int k = ks * 32 + quad * 8;
      const bf16x8 a = (ks < 4) ? ax[ks] : ah1[ks - 4];
      bf16x8 b;
      b = *(const bf16x8*)(Wih1T + (size_t)(nrow      ) * 256 + k); air = mfma16(a, b, air);
      b = *(const bf16x8*)(Wih1T + (size_t)(nrow + 128) * 256 + k); aiz = mfma16(a, b, aiz);
      b = *(const bf16x8*)(Wih1T + (size_t)(nrow + 256) * 256 + k); ain = mfma16(a, b, ain);
    }
#pragma unroll
    for (int ks = 0; ks < 4; ++ks) {   // gh1 over K=128
      const int k = ks * 32 + quad * 8;
      bf16x8 b;
      b = *(const bf16x8*)(Whh1T + (size_t)(nrow      ) * H + k); ahr = mfma16(ah1[ks], b, ahr);
      b = *(const bf16x8*)(Whh1T + (size_t)(nrow + 128) * H + k); ahz = mfma16(ah1[ks], b, ahz);
      b = *(const bf16x8*)(Whh1T + (size_t)(nrow + 256) * H + k); ahn = mfma16(ah1[ks], b, ahn);
    }
    const int col = nrow;
    const float b_ir = bih1[col],       b_hr = bhh1[col];
    const float b_iz = bih1[col + 128], b_hz = bhh1[col + 128];
    const float b_in = bih1[col + 256], b_hn = bhh1[col + 256];
    const int kb = col >> 3;
#pragma unroll
    for (int i = 0; i < 4; ++i) {
      const int r = wm * 16 + quad * 4 + i;
      const int grow = row0 + r;
      const float rr = sigm(air[i] + ahr[i] + b_ir + b_hr);
      const float zz = sigm(aiz[i] + ahz[i] + b_iz + b_hz);
      const float nn = fast_tanh(ain[i] + b_in + rr * (ahn[i] + b_hn));
      const float hv = h1[(size_t)grow * H + col];
      const float hnew = (1.0f - zz) * nn + zz * hv;
      out[OUT_H1N + (size_t)grow * H + col] = hnew;
      sC[(r * 16 + (kb ^ (r & 7))) * 8 + (col & 7)] = f2bf(0.5f * hnew + 0.25f);
    }
  }
  __syncthreads();   // sC (hc1) complete

  // ---- Head 1: v1 ----
  {
    bf16x8 ac[4];
#pragma unroll
    for (int ks = 0; ks < 4; ++ks)
      ac[ks] = *(const bf16x8*)&sC[(rA * 16 + ((ks * 4 + quad) ^ (rA & 7))) * 8];
#pragma unroll
    for (int hb = 0; hb < 2; ++hb) {
      const int colf = wn * 2 + hb;
      const int nrow = colf * 16 + l15;
      f32x4 av = {};
#pragma unroll
      for (int ks = 0; ks < 4; ++ks) {
        const int k = ks * 32 + quad * 8;
        bf16x8 b = *(const bf16x8*)(Wv1T + (size_t)nrow * H + k);
        av = mfma16(ac[ks], b, av);
      }
      const int col = nrow;
      const float bvv = bv1[col];
#pragma unroll
      for (int i = 0; i < 4; ++i) {
        const int grow = row0 + wm * 16 + quad * 4 + i;
        out[OUT_V1 + (size_t)grow * NOPT + col] = av[i] + bvv;
      }
    }
  }
}

extern "C" void kernel_launch(void* const* d_in, const int* in_sizes, int n_in,
                              void* d_out, int out_size, void* d_ws, size_t ws_size,
                              hipStream_t stream) {
  (void)in_sizes; (void)n_in; (void)out_size; (void)ws_size;
  const float* obs    = (const float*)d_in[0];
  const int*   chosen = (const int*)d_in[1];
  const float* h0     = (const float*)d_in[2];
  const float* h1     = (const float*)d_in[3];
  const float* Wa     = (const float*)d_in[4];
  const float* ba     = (const float*)d_in[5];
  const float* Wih0   = (const float*)d_in[6];
  const float* Whh0   = (const float*)d_in[7];
  const float* bih0   = (const float*)d_in[8];
  const float* bhh0   = (const float*)d_in[9];
  const float* Wih1   = (const float*)d_in[10];
  const float* Whh1   = (const float*)d_in[11];
  const float* bih1   = (const float*)d_in[12];
  const float* bhh1   = (const float*)d_in[13];
  const float* Wv0    = (const float*)d_in[14];
  const float* bv0    = (const float*)d_in[15];
  const float* Wv1    = (const float*)d_in[16];
  const float* bv1    = (const float*)d_in[17];
  const float* Wt0    = (const float*)d_in[18];
  const float* bt0    = (const float*)d_in[19];
  uint16_t* ws  = (uint16_t*)d_ws;
  float*    out = (float*)d_out;

  hipLaunchKernelGGL(k_transpose, dim3(776), dim3(256), 0, stream,
                     Wa, Wih0, Whh0, Wih1, Whh1, Wv0, Wv1, Wt0, ws);
  hipLaunchKernelGGL(k_attn, dim3(512), dim3(256), 0, stream, obs, ws, ba);
  hipLaunchKernelGGL(k_gru, dim3(256), dim3(512), 0, stream,
                     ws, h0, bih0, bhh0, bv0, bt0, chosen,
                     h1, bih1, bhh1, bv1, out);
}

// Round 5
// 499.540 us; speedup vs baseline: 1.0820x; 1.0820x over previous
//
#include <hip/hip_runtime.h>
#include <hip/hip_bf16.h>
#include <stdint.h>

// HierarchicalGRU on MI355X. B=16384, IN=4096, H=128, NOPT=64.
// Round 9: fix serialized-load latency (VGPR starvation from tight
// __launch_bounds__ caps) while keeping occupancy.
//  - Accounting model: ~297us/iter is harness workspace-poison fills; our
//    controllable budget was ~240us in R4 (attn+gru, both <158us so hidden).
//  - k_attn: R4 dbuf structure, but launch_bounds(256,2): VGPR free (~150),
//    2 blocks/CU so per-iter barrier drains overlap across blocks.
//  - k_gru: 512 blocks x 256 thr (32 rows/block), launch_bounds(256,2):
//    8-16 waves/CU AND register headroom so the 6-load gate batches pipeline.
//  - Weight-fragment loads are fully-used 64B lines (quad-groups contiguous);
//    no amplification -- prior theory retracted.

typedef __attribute__((ext_vector_type(8))) short bf16x8;
typedef __attribute__((ext_vector_type(4))) float f32x4;
typedef __attribute__((ext_vector_type(8))) float f32x8;

#define INDIM 4096
#define H 128
#define NOPT 64

// workspace layout (uint16 element offsets), bf16 contents
#define WS_WAT    0u        // [128, 4096]
#define WS_WIH0T  524288u   // [384, 128]
#define WS_WHH0T  573440u   // [384, 128]
#define WS_WIH1T  622592u   // [384, 256]
#define WS_WHH1T  720896u   // [384, 128]
#define WS_WV0T   770048u   // [64, 128]
#define WS_WV1T   778240u   // [64, 128]
#define WS_WT0T   786432u   // [64, 128]
#define WS_ATTN   794624u   // [16384, 128] bf16

// output layout (fp32 element offsets)
#define OUT_V0    0u
#define OUT_TERMP 1048576u
#define OUT_V1    1064960u
#define OUT_H0N   2113536u
#define OUT_H1N   4210688u

typedef __attribute__((address_space(1))) const void gas_t;
typedef __attribute__((address_space(3))) void las_t;
static __device__ __forceinline__ void gll16(const void* g, void* l) {
  __builtin_amdgcn_global_load_lds((gas_t*)g, (las_t*)l, 16, 0, 0);
}

static __device__ __forceinline__ uint16_t f2bf(float f) {
  __hip_bfloat16 h = __float2bfloat16(f);
  return __builtin_bit_cast(uint16_t, h);
}
static __device__ __forceinline__ float sigm(float x) { return 1.0f / (1.0f + __expf(-x)); }
static __device__ __forceinline__ float fast_tanh(float x) {
  float e = __expf(2.0f * x);
  return 1.0f - 2.0f / (e + 1.0f);
}
static __device__ __forceinline__ f32x4 mfma16(bf16x8 a, bf16x8 b, f32x4 c) {
  return __builtin_amdgcn_mfma_f32_16x16x32_bf16(a, b, c, 0, 0, 0);
}
static __device__ __forceinline__ bf16x8 cvt8(f32x8 v) {
  bf16x8 r;
#pragma unroll
  for (int j = 0; j < 8; ++j) r[j] = (short)f2bf(v[j]);
  return r;
}

// ---------------- K0: weight transpose+convert  W[K,N] fp32 -> WT[N,K] bf16 ----------------
__global__ void k_transpose(const float* __restrict__ Wa,
                            const float* __restrict__ Wih0,
                            const float* __restrict__ Whh0,
                            const float* __restrict__ Wih1,
                            const float* __restrict__ Whh1,
                            const float* __restrict__ Wv0,
                            const float* __restrict__ Wv1,
                            const float* __restrict__ Wt0,
                            uint16_t* __restrict__ ws) {
  __shared__ float sT[32][34];
  int blk = blockIdx.x;
  const float* in; uint16_t* out; int K; int N; int base;
  if (blk < 512)      { in = Wa;   out = ws + WS_WAT;   K = 4096; N = 128; base = 0; }
  else if (blk < 560) { in = Wih0; out = ws + WS_WIH0T; K = 128;  N = 384; base = 512; }
  else if (blk < 608) { in = Whh0; out = ws + WS_WHH0T; K = 128;  N = 384; base = 560; }
  else if (blk < 704) { in = Wih1; out = ws + WS_WIH1T; K = 256;  N = 384; base = 608; }
  else if (blk < 752) { in = Whh1; out = ws + WS_WHH1T; K = 128;  N = 384; base = 704; }
  else if (blk < 760) { in = Wv0;  out = ws + WS_WV0T;  K = 128;  N = 64;  base = 752; }
  else if (blk < 768) { in = Wv1;  out = ws + WS_WV1T;  K = 128;  N = 64;  base = 760; }
  else                { in = Wt0;  out = ws + WS_WT0T;  K = 128;  N = 64;  base = 768; }
  const int tix = blk - base;
  const int nTK = K >> 5;
  const int kt = tix & (nTK - 1);
  const int nt = tix / nTK;
  const int k0 = kt * 32, n0 = nt * 32;
  const int t = threadIdx.x;
#pragma unroll
  for (int i = 0; i < 4; ++i) {
    int e = i * 256 + t, kk = e >> 5, nn = e & 31;
    sT[kk][nn] = in[(size_t)(k0 + kk) * N + n0 + nn];
  }
  __syncthreads();
#pragma unroll
  for (int i = 0; i < 4; ++i) {
    int e = i * 256 + t, nn = e >> 5, kk = e & 31;
    out[(size_t)(n0 + nn) * K + k0 + kk] = f2bf(sT[kk][nn]);
  }
}

// ---------------- K1: attn = tanh(obs @ WaT^T + ba) ----------------
// 512 blocks x 256 thr (4 waves: wm=w>>1 rows, wn=w&1 col-half). M=32, BK=64.
// A: reg-staged fp32->bf16, XOR-swizzled LDS.  B: global_load_lds, linear LDS
// dest + pre-swizzled global source, swizzled ds_read (same involution).
__launch_bounds__(256, 2)
__global__ void k_attn(const float* __restrict__ obs,
                       uint16_t* __restrict__ ws,
                       const float* __restrict__ ba) {
  __shared__ __align__(16) uint16_t sA[2][32 * 8 * 8];    // [buf][(r*8+physg)*8]
  __shared__ __align__(16) uint16_t sB[2][128 * 8 * 8];   // [buf][(n*8+physg)*8]
  const uint16_t* WaT = ws + WS_WAT;
  uint16_t* attn = ws + WS_ATTN;
  const int t = threadIdx.x, w = t >> 6, lane = t & 63;
  const int l15 = lane & 15, quad = lane >> 4;
  const int wm = w >> 1, wn = w & 1;
  const int row0 = blockIdx.x * 32;
  const int rA = wm * 16 + l15;
  // A staging: thread t -> row sr, 8-elem granule sg of BK=64
  const int sr = t >> 3, sg = t & 7;
  const float* aSrc = obs + (size_t)(row0 + sr) * INDIM + sg * 8;
  const int aDst = (sr * 8 + (sg ^ (sr & 7))) * 8;
  // B staging (gll): inst j of wave w writes LDS granules (w*4+j)*64 + lane.
  const int n0 = w * 32 + (lane >> 3);
  const int gsrc = (lane & 7) ^ (n0 & 7);
  const uint16_t* bSrc = WaT + (size_t)n0 * INDIM + gsrc * 8;

  f32x4 acc[4] = {};

  auto compute = [&](int buf) {
#pragma unroll
    for (int ks = 0; ks < 2; ++ks) {
      bf16x8 a = *(const bf16x8*)&sA[buf][(rA * 8 + ((ks * 4 + quad) ^ (rA & 7))) * 8];
#pragma unroll
      for (int nb = 0; nb < 4; ++nb) {
        const int n = wn * 64 + nb * 16 + l15;
        bf16x8 b = *(const bf16x8*)&sB[buf][(n * 8 + ((ks * 4 + quad) ^ (n & 7))) * 8];
        acc[nb] = mfma16(a, b, acc[nb]);
      }
    }
  };

  // prologue: stage tile 0 into buf 0
  {
    f32x8 av = *(const f32x8*)aSrc;
#pragma unroll
    for (int j = 0; j < 4; ++j)
      gll16(bSrc + (size_t)j * 8 * INDIM, (void*)&sB[0][(w * 4 + j) * 512]);
    *(bf16x8*)&sA[0][aDst] = cvt8(av);
  }
  __syncthreads();

  for (int kt = 0; kt < 63; ++kt) {
    const int cur = kt & 1, nxt = cur ^ 1;
    // issue next tile's loads; they fly during compute
    f32x8 av = *(const f32x8*)(aSrc + (size_t)(kt + 1) * 64);
#pragma unroll
    for (int j = 0; j < 4; ++j)
      gll16(bSrc + (size_t)(kt + 1) * 64 + (size_t)j * 8 * INDIM,
            (void*)&sB[nxt][(w * 4 + j) * 512]);
    compute(cur);
    *(bf16x8*)&sA[nxt][aDst] = cvt8(av);
    __syncthreads();
  }
  compute(1);   // tile 63 lives in buf 1

  // epilogue: tanh + bias -> attn (bf16) in ws
#pragma unroll
  for (int nb = 0; nb < 4; ++nb) {
    const int col = wn * 64 + nb * 16 + l15;
    const float bav = ba[col];
#pragma unroll
    for (int i = 0; i < 4; ++i) {
      const int r = wm * 16 + quad * 4 + i;
      attn[(size_t)(row0 + r) * H + col] = f2bf(fast_tanh(acc[nb][i] + bav));
    }
  }
}

// ---------------- K2: GRU0 + heads + GRU1 ----------------
// 512 blocks x 256 thr (4 waves: wm=w>>1 row-group, wn=w&1 gate-col-half).
// launch_bounds(256,2): register headroom so load batches pipeline.
__launch_bounds__(256, 2)
__global__ void k_gru(const uint16_t* __restrict__ ws,
                      const float* __restrict__ h0,
                      const float* __restrict__ bih0,
                      const float* __restrict__ bhh0,
                      const float* __restrict__ bv0,
                      const float* __restrict__ bt0,
                      const int* __restrict__ chosen,
                      const float* __restrict__ h1,
                      const float* __restrict__ bih1,
                      const float* __restrict__ bhh1,
                      const float* __restrict__ bv1,
                      float* __restrict__ out) {
  __shared__ __align__(16) uint16_t sC[32 * 16 * 8];   // hc tile, swizzled; 8 KB
  const uint16_t* attn  = ws + WS_ATTN;
  const uint16_t* Wih0T = ws + WS_WIH0T;
  const uint16_t* Whh0T = ws + WS_WHH0T;
  const uint16_t* Wih1T = ws + WS_WIH1T;
  const uint16_t* Whh1T = ws + WS_WHH1T;
  const uint16_t* Wv0T  = ws + WS_WV0T;
  const uint16_t* Wv1T  = ws + WS_WV1T;
  const uint16_t* Wt0T  = ws + WS_WT0T;
  const int t = threadIdx.x, w = t >> 6, lane = t & 63;
  const int l15 = lane & 15, quad = lane >> 4;
  const int wm = w >> 1, wn = w & 1;
  const int row0 = blockIdx.x * 32;
  const int rA = wm * 16 + l15;

  // A-frags: attn (bf16, from ws) + h0 (fp32 -> bf16)
  bf16x8 ax[4], ah[4];
#pragma unroll
  for (int ks = 0; ks < 4; ++ks) {
    ax[ks] = *(const bf16x8*)(attn + (size_t)(row0 + rA) * H + ks * 32 + quad * 8);
    ah[ks] = cvt8(*(const f32x8*)(h0 + (size_t)(row0 + rA) * H + ks * 32 + quad * 8));
  }

  // ---- Phase B: GRU layer 0, wave covers gate cols [64wn, 64wn+64) ----
#pragma unroll
  for (int nbl = 0; nbl < 4; ++nbl) {
    const int nb = wn * 4 + nbl;
    const int nrow = nb * 16 + l15;
    f32x4 air = {}, ahr = {}, aiz = {}, ahz = {}, ain = {}, ahn = {};
#pragma unroll
    for (int ks = 0; ks < 4; ++ks) {
      const int k = ks * 32 + quad * 8;
      bf16x8 b0 = *(const bf16x8*)(Wih0T + (size_t)(nrow      ) * H + k);
      bf16x8 b1 = *(const bf16x8*)(Wih0T + (size_t)(nrow + 128) * H + k);
      bf16x8 b2 = *(const bf16x8*)(Wih0T + (size_t)(nrow + 256) * H + k);
      bf16x8 b3 = *(const bf16x8*)(Whh0T + (size_t)(nrow      ) * H + k);
      bf16x8 b4 = *(const bf16x8*)(Whh0T + (size_t)(nrow + 128) * H + k);
      bf16x8 b5 = *(const bf16x8*)(Whh0T + (size_t)(nrow + 256) * H + k);
      air = mfma16(ax[ks], b0, air);
      aiz = mfma16(ax[ks], b1, aiz);
      ain = mfma16(ax[ks], b2, ain);
      ahr = mfma16(ah[ks], b3, ahr);
      ahz = mfma16(ah[ks], b4, ahz);
      ahn = mfma16(ah[ks], b5, ahn);
    }
    const int col = nrow;
    const float b_ir = bih0[col],       b_hr = bhh0[col];
    const float b_iz = bih0[col + 128], b_hz = bhh0[col + 128];
    const float b_in = bih0[col + 256], b_hn = bhh0[col + 256];
    const int kb = col >> 3;
#pragma unroll
    for (int i = 0; i < 4; ++i) {
      const int r = wm * 16 + quad * 4 + i;
      const int grow = row0 + r;
      const float rr = sigm(air[i] + ahr[i] + b_ir + b_hr);
      const float zz = sigm(aiz[i] + ahz[i] + b_iz + b_hz);
      const float nn = fast_tanh(ain[i] + b_in + rr * (ahn[i] + b_hn));
      const float hv = h0[(size_t)grow * H + col];
      const float hnew = (1.0f - zz) * nn + zz * hv;
      out[OUT_H0N + (size_t)grow * H + col] = hnew;
      sC[(r * 16 + (kb ^ (r & 7))) * 8 + (col & 7)] = f2bf(0.5f * hnew + 0.25f);
    }
  }
  __syncthreads();   // sC (hc0) complete

  // ---- Heads 0: v0 + term. Wave covers col-frags {2wn, 2wn+1} for its rows ----
  {
    bf16x8 ac[4];
#pragma unroll
    for (int ks = 0; ks < 4; ++ks)
      ac[ks] = *(const bf16x8*)&sC[(rA * 16 + ((ks * 4 + quad) ^ (rA & 7))) * 8];
    int ch[4];
#pragma unroll
    for (int i = 0; i < 4; ++i) ch[i] = chosen[row0 + wm * 16 + quad * 4 + i];
#pragma unroll
    for (int hb = 0; hb < 2; ++hb) {
      const int colf = wn * 2 + hb;
      const int nrow = colf * 16 + l15;
      f32x4 av = {}, at = {};
#pragma unroll
      for (int ks = 0; ks < 4; ++ks) {
        const int k = ks * 32 + quad * 8;
        bf16x8 b0 = *(const bf16x8*)(Wv0T + (size_t)nrow * H + k);
        bf16x8 b1 = *(const bf16x8*)(Wt0T + (size_t)nrow * H + k);
        av = mfma16(ac[ks], b0, av);
        at = mfma16(ac[ks], b1, at);
      }
      const int col = nrow;
      const float bvv = bv0[col], btv = bt0[col];
#pragma unroll
      for (int i = 0; i < 4; ++i) {
        const int grow = row0 + wm * 16 + quad * 4 + i;
        out[OUT_V0 + (size_t)grow * NOPT + col] = av[i] + bvv;
        if (ch[i] == col)
          out[OUT_TERMP + grow] = sigm(at[i] + btv);
      }
    }
  }
  __syncthreads();   // heads-0 reads done; sC reusable

  // ---- Phase C: GRU layer 1 (x1 = [attn | h1]) ----
  bf16x8 ah1[4];
#pragma unroll
  for (int ks = 0; ks < 4; ++ks)
    ah1[ks] = cvt8(*(const f32x8*)(h1 + (size_t)(row0 + rA) * H + ks * 32 + quad * 8));
#pragma unroll
  for (int nbl = 0; nbl < 4; ++nbl) {
    const int nb = wn * 4 + nbl;
    const int nrow = nb * 16 + l15;
    f32x4 air = {}, ahr = {}, aiz = {}, ahz = {}, ain = {}, ahn = {};
#pragma unroll
    for (int ks = 0; ks < 8; ++ks) {   // gi1 over K=256
      const int k = ks * 32 + quad * 8;
      const bf16x8 a = (ks < 4) ? ax[ks] : ah1[ks - 4];
      bf16x8 b0 = *(const bf16x8*)(Wih1T + (size_t)(nrow      ) * 256 + k);
      bf16x8 b1 = *(const bf16x8*)(Wih1T + (size_t)(nrow + 128) * 256 + k);
      bf16x8 b2 = *(const bf16x8*)(Wih1T + (size_t)(nrow + 256) * 256 + k);
      air = mfma16(a, b0, air);
      aiz = mfma16(a, b1, aiz);
      ain = mfma16(a, b2, ain);
    }
#pragma unroll
    for (int ks = 0; ks < 4; ++ks) {   // gh1 over K=128
      const int k = ks * 32 + quad * 8;
      bf16x8 b0 = *(const bf16x8*)(Whh1T + (size_t)(nrow      ) * H + k);
      bf16x8 b1 = *(const bf16x8*)(Whh1T + (size_t)(nrow + 128) * H + k);
      bf16x8 b2 = *(const bf16x8*)(Whh1T + (size_t)(nrow + 256) * H + k);
      ahr = mfma16(ah1[ks], b0, ahr);
      ahz = mfma16(ah1[ks], b1, ahz);
      ahn = mfma16(ah1[ks], b2, ahn);
    }
    const int col = nrow;
    const float b_ir = bih1[col],       b_hr = bhh1[col];
    const float b_iz = bih1[col + 128], b_hz = bhh1[col + 128];
    const float b_in = bih1[col + 256], b_hn = bhh1[col + 256];
    const int kb = col >> 3;
#pragma unroll
    for (int i = 0; i < 4; ++i) {
      const int r = wm * 16 + quad * 4 + i;
      const int grow = row0 + r;
      const float rr = sigm(air[i] + ahr[i] + b_ir + b_hr);
      const float zz = sigm(aiz[i] + ahz[i] + b_iz + b_hz);
      const float nn = fast_tanh(ain[i] + b_in + rr * (ahn[i] + b_hn));
      const float hv = h1[(size_t)grow * H + col];
      const float hnew = (1.0f - zz) * nn + zz * hv;
      out[OUT_H1N + (size_t)grow * H + col] = hnew;
      sC[(r * 16 + (kb ^ (r & 7))) * 8 + (col & 7)] = f2bf(0.5f * hnew + 0.25f);
    }
  }
  __syncthreads();   // sC (hc1) complete

  // ---- Head 1: v1 ----
  {
    bf16x8 ac[4];
#pragma unroll
    for (int ks = 0; ks < 4; ++ks)
      ac[ks] = *(const bf16x8*)&sC[(rA * 16 + ((ks * 4 + quad) ^ (rA & 7))) * 8];
#pragma unroll
    for (int hb = 0; hb < 2; ++hb) {
      const int colf = wn * 2 + hb;
      const int nrow = colf * 16 + l15;
      f32x4 av = {};
#pragma unroll
      for (int ks = 0; ks < 4; ++ks) {
        const int k = ks * 32 + quad * 8;
        bf16x8 b = *(const bf16x8*)(Wv1T + (size_t)nrow * H + k);
        av = mfma16(ac[ks], b, av);
      }
      const int col = nrow;
      const float bvv = bv1[col];
#pragma unroll
      for (int i = 0; i < 4; ++i) {
        const int grow = row0 + wm * 16 + quad * 4 + i;
        out[OUT_V1 + (size_t)grow * NOPT + col] = av[i] + bvv;
      }
    }
  }
}

extern "C" void kernel_launch(void* const* d_in, const int* in_sizes, int n_in,
                              void* d_out, int out_size, void* d_ws, size_t ws_size,
                              hipStream_t stream) {
  (void)in_sizes; (void)n_in; (void)out_size; (void)ws_size;
  const float* obs    = (const float*)d_in[0];
  const int*   chosen = (const int*)d_in[1];
  const float* h0     = (const float*)d_in[2];
  const float* h1     = (const float*)d_in[3];
  const float* Wa     = (const float*)d_in[4];
  const float* ba     = (const float*)d_in[5];
  const float* Wih0   = (const float*)d_in[6];
  const float* Whh0   = (const float*)d_in[7];
  const float* bih0   = (const float*)d_in[8];
  const float* bhh0   = (const float*)d_in[9];
  const float* Wih1   = (const float*)d_in[10];
  const float* Whh1   = (const float*)d_in[11];
  const float* bih1   = (const float*)d_in[12];
  const float* bhh1   = (const float*)d_in[13];
  const float* Wv0    = (const float*)d_in[14];
  const float* bv0    = (const float*)d_in[15];
  const float* Wv1    = (const float*)d_in[16];
  const float* bv1    = (const float*)d_in[17];
  const float* Wt0    = (const float*)d_in[18];
  const float* bt0    = (const float*)d_in[19];
  uint16_t* ws  = (uint16_t*)d_ws;
  float*    out = (float*)d_out;

  hipLaunchKernelGGL(k_transpose, dim3(776), dim3(256), 0, stream,
                     Wa, Wih0, Whh0, Wih1, Whh1, Wv0, Wv1, Wt0, ws);
  hipLaunchKernelGGL(k_attn, dim3(512), dim3(256), 0, stream, obs, ws, ba);
  hipLaunchKernelGGL(k_gru, dim3(512), dim3(256), 0, stream,
                     ws, h0, bih0, bhh0, bv0, bt0, chosen,
                     h1, bih1, bhh1, bv1, out);
}

// Round 7
// 499.031 us; speedup vs baseline: 1.0831x; 1.0010x over previous
//
#include <hip/hip_runtime.h>
#include <hip/hip_bf16.h>
#include <stdint.h>

// HierarchicalGRU on MI355X. B=16384, IN=4096, H=128, NOPT=64.
// Round 11 (= R10 resubmit after container-level infra failure; bounds +
// FIFO-count + barrier-uniformity audited, no kernel-attributable fault):
//  k_attn: counted-vmcnt pipeline (T3/T4, m218):
//  - raw s_barrier + s_waitcnt vmcnt(8) (never 0 in steady state): tile t+2
//    loads stay in flight across barriers; tile t+1 guaranteed landed.
//  - A (obs): direct per-lane to registers, 4-slot rotation, fully static
//    indices (rule #20). No LDS for A.
//  - B (WaT): global_load_lds into 4 LDS buffers (64 KB), XOR-swizzled reads.
//  - VMEM events per iter = 4 (A f32x4) + 4 (gll) = 8 exactly -> vmcnt(8).
//  - sched_barrier(0) fences around each wait+barrier (rule #18).
// k_transpose / k_gru unchanged from round 9 (verified numerics).

typedef __attribute__((ext_vector_type(8))) short bf16x8;
typedef __attribute__((ext_vector_type(4))) float f32x4;
typedef __attribute__((ext_vector_type(8))) float f32x8;

#define INDIM 4096
#define H 128
#define NOPT 64

// workspace layout (uint16 element offsets), bf16 contents
#define WS_WAT    0u        // [128, 4096]
#define WS_WIH0T  524288u   // [384, 128]
#define WS_WHH0T  573440u   // [384, 128]
#define WS_WIH1T  622592u   // [384, 256]
#define WS_WHH1T  720896u   // [384, 128]
#define WS_WV0T   770048u   // [64, 128]
#define WS_WV1T   778240u   // [64, 128]
#define WS_WT0T   786432u   // [64, 128]
#define WS_ATTN   794624u   // [16384, 128] bf16

// output layout (fp32 element offsets)
#define OUT_V0    0u
#define OUT_TERMP 1048576u
#define OUT_V1    1064960u
#define OUT_H0N   2113536u
#define OUT_H1N   4210688u

typedef __attribute__((address_space(1))) const void gas_t;
typedef __attribute__((address_space(3))) void las_t;
static __device__ __forceinline__ void gll16(const void* g, void* l) {
  __builtin_amdgcn_global_load_lds((gas_t*)g, (las_t*)l, 16, 0, 0);
}

static __device__ __forceinline__ uint16_t f2bf(float f) {
  __hip_bfloat16 h = __float2bfloat16(f);
  return __builtin_bit_cast(uint16_t, h);
}
static __device__ __forceinline__ float sigm(float x) { return 1.0f / (1.0f + __expf(-x)); }
static __device__ __forceinline__ float fast_tanh(float x) {
  float e = __expf(2.0f * x);
  return 1.0f - 2.0f / (e + 1.0f);
}
static __device__ __forceinline__ f32x4 mfma16(bf16x8 a, bf16x8 b, f32x4 c) {
  return __builtin_amdgcn_mfma_f32_16x16x32_bf16(a, b, c, 0, 0, 0);
}
static __device__ __forceinline__ bf16x8 cvt8(f32x8 v) {
  bf16x8 r;
#pragma unroll
  for (int j = 0; j < 8; ++j) r[j] = (short)f2bf(v[j]);
  return r;
}
static __device__ __forceinline__ bf16x8 cvt8p(f32x4 lo, f32x4 hi) {
  bf16x8 r;
  r[0] = (short)f2bf(lo[0]); r[1] = (short)f2bf(lo[1]);
  r[2] = (short)f2bf(lo[2]); r[3] = (short)f2bf(lo[3]);
  r[4] = (short)f2bf(hi[0]); r[5] = (short)f2bf(hi[1]);
  r[6] = (short)f2bf(hi[2]); r[7] = (short)f2bf(hi[3]);
  return r;
}

// ---------------- K0: weight transpose+convert  W[K,N] fp32 -> WT[N,K] bf16 ----------------
__global__ void k_transpose(const float* __restrict__ Wa,
                            const float* __restrict__ Wih0,
                            const float* __restrict__ Whh0,
                            const float* __restrict__ Wih1,
                            const float* __restrict__ Whh1,
                            const float* __restrict__ Wv0,
                            const float* __restrict__ Wv1,
                            const float* __restrict__ Wt0,
                            uint16_t* __restrict__ ws) {
  __shared__ float sT[32][34];
  int blk = blockIdx.x;
  const float* in; uint16_t* out; int K; int N; int base;
  if (blk < 512)      { in = Wa;   out = ws + WS_WAT;   K = 4096; N = 128; base = 0; }
  else if (blk < 560) { in = Wih0; out = ws + WS_WIH0T; K = 128;  N = 384; base = 512; }
  else if (blk < 608) { in = Whh0; out = ws + WS_WHH0T; K = 128;  N = 384; base = 560; }
  else if (blk < 704) { in = Wih1; out = ws + WS_WIH1T; K = 256;  N = 384; base = 608; }
  else if (blk < 752) { in = Whh1; out = ws + WS_WHH1T; K = 128;  N = 384; base = 704; }
  else if (blk < 760) { in = Wv0;  out = ws + WS_WV0T;  K = 128;  N = 64;  base = 752; }
  else if (blk < 768) { in = Wv1;  out = ws + WS_WV1T;  K = 128;  N = 64;  base = 760; }
  else                { in = Wt0;  out = ws + WS_WT0T;  K = 128;  N = 64;  base = 768; }
  const int tix = blk - base;
  const int nTK = K >> 5;
  const int kt = tix & (nTK - 1);
  const int nt = tix / nTK;
  const int k0 = kt * 32, n0 = nt * 32;
  const int t = threadIdx.x;
#pragma unroll
  for (int i = 0; i < 4; ++i) {
    int e = i * 256 + t, kk = e >> 5, nn = e & 31;
    sT[kk][nn] = in[(size_t)(k0 + kk) * N + n0 + nn];
  }
  __syncthreads();
#pragma unroll
  for (int i = 0; i < 4; ++i) {
    int e = i * 256 + t, nn = e >> 5, kk = e & 31;
    out[(size_t)(n0 + nn) * K + k0 + kk] = f2bf(sT[kk][nn]);
  }
}

// ---------------- K1: attn = tanh(obs @ WaT^T + ba) ----------------
// 512 blocks x 256 thr (4 waves: wm=w>>1 rows, wn=w&1 col-half). BM=32, BK=64.
// Counted-vmcnt 2-deep pipeline, 4 LDS buffers, raw s_barrier (never vmcnt(0)
// in steady state). A in registers (4-slot rotation), B via global_load_lds.
__launch_bounds__(256, 2)
__global__ void k_attn(const float* __restrict__ obs,
                       uint16_t* __restrict__ ws,
                       const float* __restrict__ ba) {
  __shared__ __align__(16) uint16_t sB[4][128 * 64];   // 64 KB
  const uint16_t* WaT = ws + WS_WAT;
  uint16_t* attn = ws + WS_ATTN;
  const int t = threadIdx.x, w = t >> 6, lane = t & 63;
  const int l15 = lane & 15, quad = lane >> 4;
  const int wm = w >> 1, wn = w & 1;
  const int row0 = blockIdx.x * 32;
  // A: per-lane direct; lane covers row (row0+wm*16+l15), k = kt*64 + ks*32 + quad*8
  const float* aPtr = obs + (size_t)(row0 + wm * 16 + l15) * INDIM + quad * 8;
  // B gll mapping (R5-verified): inst j of wave w writes LDS granules (w*4+j)*64+lane;
  // physical granule lane&7 of row n0 = w*32+j*8+(lane>>3); source granule = (lane&7)^(n0&7).
  const int n0 = w * 32 + (lane >> 3);
  const int gsrc = (lane & 7) ^ (n0 & 7);
  const uint16_t* bSrc = WaT + (size_t)n0 * INDIM + gsrc * 8;

  f32x4 acc[4] = {};
  f32x4 A0[4], A1[4], A2[4], A3[4];   // slot: [ks0 lo, ks0 hi, ks1 lo, ks1 hi]

#define ISSUE_A(S, tt) do {                                     \
    S[0] = *(const f32x4*)(aPtr + (size_t)(tt) * 64);           \
    S[1] = *(const f32x4*)(aPtr + (size_t)(tt) * 64 + 4);       \
    S[2] = *(const f32x4*)(aPtr + (size_t)(tt) * 64 + 32);      \
    S[3] = *(const f32x4*)(aPtr + (size_t)(tt) * 64 + 36);      \
  } while (0)
#define ISSUE_B(bufj, tt) do {                                              \
    _Pragma("unroll")                                                       \
    for (int j = 0; j < 4; ++j)                                             \
      gll16(bSrc + (size_t)(tt) * 64 + (size_t)j * 8 * INDIM,               \
            (void*)&sB[bufj][(w * 4 + j) * 512]);                           \
  } while (0)
#define COMPUTE(S, bufj) do {                                               \
    _Pragma("unroll")                                                       \
    for (int ks = 0; ks < 2; ++ks) {                                        \
      bf16x8 a = cvt8p(S[ks * 2], S[ks * 2 + 1]);                           \
      _Pragma("unroll")                                                     \
      for (int nb = 0; nb < 4; ++nb) {                                      \
        const int n = wn * 64 + nb * 16 + l15;                              \
        bf16x8 b = *(const bf16x8*)                                         \
            &sB[bufj][(n * 8 + ((ks * 4 + quad) ^ (n & 7))) * 8];           \
        acc[nb] = mfma16(a, b, acc[nb]);                                    \
      }                                                                     \
    }                                                                       \
  } while (0)
// counted wait + raw barrier; sched_barrier fences stop hipcc reordering (rule #18)
#define BARN(N) do {                                                        \
    asm volatile("s_waitcnt vmcnt(" #N ")" ::: "memory");                   \
    __builtin_amdgcn_sched_barrier(0);                                      \
    __builtin_amdgcn_s_barrier();                                           \
    __builtin_amdgcn_sched_barrier(0);                                      \
  } while (0)

  // Prologue: tiles 0,1 in flight (16 events); vmcnt(8) => tile-0's 8 events
  // (A0 x4 + gll0 x4) complete for THIS wave; s_barrier => for ALL waves.
  ISSUE_A(A0, 0); ISSUE_B(0, 0);
  ISSUE_A(A1, 1); ISSUE_B(1, 1);
  BARN(8);
  // Steady state: iter t issues tile t+2 (8 events), computes tile t; then
  // vmcnt(8) leaves only tile t+2 outstanding => tile t+1 landed; barrier.
  for (int kt4 = 0; kt4 < 60; kt4 += 4) {
    ISSUE_A(A2, kt4 + 2); ISSUE_B(2, kt4 + 2); COMPUTE(A0, 0); BARN(8);
    ISSUE_A(A3, kt4 + 3); ISSUE_B(3, kt4 + 3); COMPUTE(A1, 1); BARN(8);
    ISSUE_A(A0, kt4 + 4); ISSUE_B(0, kt4 + 4); COMPUTE(A2, 2); BARN(8);
    ISSUE_A(A1, kt4 + 5); ISSUE_B(1, kt4 + 5); COMPUTE(A3, 3); BARN(8);
  }
  // Epilogue: tiles 60..63 live in slots A0..A3 / bufs 0..3.
  ISSUE_A(A2, 62); ISSUE_B(2, 62); COMPUTE(A0, 0); BARN(8);
  ISSUE_A(A3, 63); ISSUE_B(3, 63); COMPUTE(A1, 1); BARN(8);
  COMPUTE(A2, 2); BARN(0);
  COMPUTE(A3, 3);
#undef ISSUE_A
#undef ISSUE_B
#undef COMPUTE
#undef BARN

  // epilogue: tanh + bias -> attn (bf16) in ws
#pragma unroll
  for (int nb = 0; nb < 4; ++nb) {
    const int col = wn * 64 + nb * 16 + l15;
    const float bav = ba[col];
#pragma unroll
    for (int i = 0; i < 4; ++i) {
      const int r = wm * 16 + quad * 4 + i;
      attn[(size_t)(row0 + r) * H + col] = f2bf(fast_tanh(acc[nb][i] + bav));
    }
  }
}

// ---------------- K2: GRU0 + heads + GRU1 ----------------
// 512 blocks x 256 thr (4 waves: wm=w>>1 row-group, wn=w&1 gate-col-half).
__launch_bounds__(256, 2)
__global__ void k_gru(const uint16_t* __restrict__ ws,
                      const float* __restrict__ h0,
                      const float* __restrict__ bih0,
                      const float* __restrict__ bhh0,
                      const float* __restrict__ bv0,
                      const float* __restrict__ bt0,
                      const int* __restrict__ chosen,
                      const float* __restrict__ h1,
                      const float* __restrict__ bih1,
                      const float* __restrict__ bhh1,
                      const float* __restrict__ bv1,
                      float* __restrict__ out) {
  __shared__ __align__(16) uint16_t sC[32 * 16 * 8];   // hc tile, swizzled; 8 KB
  const uint16_t* attn  = ws + WS_ATTN;
  const uint16_t* Wih0T = ws + WS_WIH0T;
  const uint16_t* Whh0T = ws + WS_WHH0T;
  const uint16_t* Wih1T = ws + WS_WIH1T;
  const uint16_t* Whh1T = ws + WS_WHH1T;
  const uint16_t* Wv0T  = ws + WS_WV0T;
  const uint16_t* Wv1T  = ws + WS_WV1T;
  const uint16_t* Wt0T  = ws + WS_WT0T;
  const int t = threadIdx.x, w = t >> 6, lane = t & 63;
  const int l15 = lane & 15, quad = lane >> 4;
  const int wm = w >> 1, wn = w & 1;
  const int row0 = blockIdx.x * 32;
  const int rA = wm * 16 + l15;

  bf16x8 ax[4], ah[4];
#pragma unroll
  for (int ks = 0; ks < 4; ++ks) {
    ax[ks] = *(const bf16x8*)(attn + (size_t)(row0 + rA) * H + ks * 32 + quad * 8);
    ah[ks] = cvt8(*(const f32x8*)(h0 + (size_t)(row0 + rA) * H + ks * 32 + quad * 8));
  }

  // ---- GRU layer 0, wave covers gate cols [64wn, 64wn+64) ----
#pragma unroll
  for (int nbl = 0; nbl < 4; ++nbl) {
    const int nb = wn * 4 + nbl;
    const int nrow = nb * 16 + l15;
    f32x4 air = {}, ahr = {}, aiz = {}, ahz = {}, ain = {}, ahn = {};
#pragma unroll
    for (int ks = 0; ks < 4; ++ks) {
      const int k = ks * 32 + quad * 8;
      bf16x8 b0 = *(const bf16x8*)(Wih0T + (size_t)(nrow      ) * H + k);
      bf16x8 b1 = *(const bf16x8*)(Wih0T + (size_t)(nrow + 128) * H + k);
      bf16x8 b2 = *(const bf16x8*)(Wih0T + (size_t)(nrow + 256) * H + k);
      bf16x8 b3 = *(const bf16x8*)(Whh0T + (size_t)(nrow      ) * H + k);
      bf16x8 b4 = *(const bf16x8*)(Whh0T + (size_t)(nrow + 128) * H + k);
      bf16x8 b5 = *(const bf16x8*)(Whh0T + (size_t)(nrow + 256) * H + k);
      air = mfma16(ax[ks], b0, air);
      aiz = mfma16(ax[ks], b1, aiz);
      ain = mfma16(ax[ks], b2, ain);
      ahr = mfma16(ah[ks], b3, ahr);
      ahz = mfma16(ah[ks], b4, ahz);
      ahn = mfma16(ah[ks], b5, ahn);
    }
    const int col = nrow;
    const float b_ir = bih0[col],       b_hr = bhh0[col];
    const float b_iz = bih0[col + 128], b_hz = bhh0[col + 128];
    const float b_in = bih0[col + 256], b_hn = bhh0[col + 256];
    const int kb = col >> 3;
#pragma unroll
    for (int i = 0; i < 4; ++i) {
      const int r = wm * 16 + quad * 4 + i;
      const int grow = row0 + r;
      const float rr = sigm(air[i] + ahr[i] + b_ir + b_hr);
      const float zz = sigm(aiz[i] + ahz[i] + b_iz + b_hz);
      const float nn = fast_tanh(ain[i] + b_in + rr * (ahn[i] + b_hn));
      const float hv = h0[(size_t)grow * H + col];
      const float hnew = (1.0f - zz) * nn + zz * hv;
      out[OUT_H0N + (size_t)grow * H + col] = hnew;
      sC[(r * 16 + (kb ^ (r & 7))) * 8 + (col & 7)] = f2bf(0.5f * hnew + 0.25f);
    }
  }
  __syncthreads();   // sC (hc0) complete

  // ---- Heads 0: v0 + term ----
  {
    bf16x8 ac[4];
#pragma unroll
    for (int ks = 0; ks < 4; ++ks)
      ac[ks] = *(const bf16x8*)&sC[(rA * 16 + ((ks * 4 + quad) ^ (rA & 7))) * 8];
    int ch[4];
#pragma unroll
    for (int i = 0; i < 4; ++i) ch[i] = chosen[row0 + wm * 16 + quad * 4 + i];
#pragma unroll
    for (int hb = 0; hb < 2; ++hb) {
      const int colf = wn * 2 + hb;
      const int nrow = colf * 16 + l15;
      f32x4 av = {}, at = {};
#pragma unroll
      for (int ks = 0; ks < 4; ++ks) {
        const int k = ks * 32 + quad * 8;
        bf16x8 b0 = *(const bf16x8*)(Wv0T + (size_t)nrow * H + k);
        bf16x8 b1 = *(const bf16x8*)(Wt0T + (size_t)nrow * H + k);
        av = mfma16(ac[ks], b0, av);
        at = mfma16(ac[ks], b1, at);
      }
      const int col = nrow;
      const float bvv = bv0[col], btv = bt0[col];
#pragma unroll
      for (int i = 0; i < 4; ++i) {
        const int grow = row0 + wm * 16 + quad * 4 + i;
        out[OUT_V0 + (size_t)grow * NOPT + col] = av[i] + bvv;
        if (ch[i] == col)
          out[OUT_TERMP + grow] = sigm(at[i] + btv);
      }
    }
  }
  __syncthreads();   // heads-0 reads done; sC reusable

  // ---- GRU layer 1 (x1 = [attn | h1]) ----
  bf16x8 ah1[4];
#pragma unroll
  for (int ks = 0; ks < 4; ++ks)
    ah1[ks] = cvt8(*(const f32x8*)(h1 + (size_t)(row0 + rA) * H + ks * 32 + quad * 8));
#pragma unroll
  for (int nbl = 0; nbl < 4; ++nbl) {
    const int nb = wn * 4 + nbl;
    const int nrow = nb * 16 + l15;
    f32x4 air = {}, ahr = {}, aiz = {}, ahz = {}, ain = {}, ahn = {};
#pragma unroll
    for (int ks = 0; ks < 8; ++ks) {   // gi1 over K=256
      const int k = ks * 32 + quad * 8;
      const bf16x8 a = (ks < 4) ? ax[ks] : ah1[ks - 4];
      bf16x8 b0 = *(const bf16x8*)(Wih1T + (size_t)(nrow      ) * 256 + k);
      bf16x8 b1 = *(const bf16x8*)(Wih1T + (size_t)(nrow + 128) * 256 + k);
      bf16x8 b2 = *(const bf16x8*)(Wih1T + (size_t)(nrow + 256) * 256 + k);
      air = mfma16(a, b0, air);
      aiz = mfma16(a, b1, aiz);
      ain = mfma16(a, b2, ain);
    }
#pragma unroll
    for (int ks = 0; ks < 4; ++ks) {   // gh1 over K=128
      const int k = ks * 32 + quad * 8;
      bf16x8 b0 = *(const bf16x8*)(Whh1T + (size_t)(nrow      ) * H + k);
      bf16x8 b1 = *(const bf16x8*)(Whh1T + (size_t)(nrow + 128) * H + k);
      bf16x8 b2 = *(const bf16x8*)(Whh1T + (size_t)(nrow + 256) * H + k);
      ahr = mfma16(ah1[ks], b0, ahr);
      ahz = mfma16(ah1[ks], b1, ahz);
      ahn = mfma16(ah1[ks], b2, ahn);
    }
    const int col = nrow;
    const float b_ir = bih1[col],       b_hr = bhh1[col];
    const float b_iz = bih1[col + 128], b_hz = bhh1[col + 128];
    const float b_in = bih1[col + 256], b_hn = bhh1[col + 256];
    const int kb = col >> 3;
#pragma unroll
    for (int i = 0; i < 4; ++i) {
      const int r = wm * 16 + quad * 4 + i;
      const int grow = row0 + r;
      const float rr = sigm(air[i] + ahr[i] + b_ir + b_hr);
      const float zz = sigm(aiz[i] + ahz[i] + b_iz + b_hz);
      const float nn = fast_tanh(ain[i] + b_in + rr * (ahn[i] + b_hn));
      const float hv = h1[(size_t)grow * H + col];
      const float hnew = (1.0f - zz) * nn + zz * hv;
      out[OUT_H1N + (size_t)grow * H + col] = hnew;
      sC[(r * 16 + (kb ^ (r & 7))) * 8 + (col & 7)] = f2bf(0.5f * hnew + 0.25f);
    }
  }
  __syncthreads();   // sC (hc1) complete

  // ---- Head 1: v1 ----
  {
    bf16x8 ac[4];
#pragma unroll
    for (int ks = 0; ks < 4; ++ks)
      ac[ks] = *(const bf16x8*)&sC[(rA * 16 + ((ks * 4 + quad) ^ (rA & 7))) * 8];
#pragma unroll
    for (int hb = 0; hb < 2; ++hb) {
      const int colf = wn * 2 + hb;
      const int nrow = colf * 16 + l15;
      f32x4 av = {};
#pragma unroll
      for (int ks = 0; ks < 4; ++ks) {
        const int k = ks * 32 + quad * 8;
        bf16x8 b = *(const bf16x8*)(Wv1T + (size_t)nrow * H + k);
        av = mfma16(ac[ks], b, av);
      }
      const int col = nrow;
      const float bvv = bv1[col];
#pragma unroll
      for (int i = 0; i < 4; ++i) {
        const int grow = row0 + wm * 16 + quad * 4 + i;
        out[OUT_V1 + (size_t)grow * NOPT + col] = av[i] + bvv;
      }
    }
  }
}

extern "C" void kernel_launch(void* const* d_in, const int* in_sizes, int n_in,
                              void* d_out, int out_size, void* d_ws, size_t ws_size,
                              hipStream_t stream) {
  (void)in_sizes; (void)n_in; (void)out_size; (void)ws_size;
  const float* obs    = (const float*)d_in[0];
  const int*   chosen = (const int*)d_in[1];
  const float* h0     = (const float*)d_in[2];
  const float* h1     = (const float*)d_in[3];
  const float* Wa     = (const float*)d_in[4];
  const float* ba     = (const float*)d_in[5];
  const float* Wih0   = (const float*)d_in[6];
  const float* Whh0   = (const float*)d_in[7];
  const float* bih0   = (const float*)d_in[8];
  const float* bhh0   = (const float*)d_in[9];
  const float* Wih1   = (const float*)d_in[10];
  const float* Whh1   = (const float*)d_in[11];
  const float* bih1   = (const float*)d_in[12];
  const float* bhh1   = (const float*)d_in[13];
  const float* Wv0    = (const float*)d_in[14];
  const float* bv0    = (const float*)d_in[15];
  const float* Wv1    = (const float*)d_in[16];
  const float* bv1    = (const float*)d_in[17];
  const float* Wt0    = (const float*)d_in[18];
  const float* bt0    = (const float*)d_in[19];
  uint16_t* ws  = (uint16_t*)d_ws;
  float*    out = (float*)d_out;

  hipLaunchKernelGGL(k_transpose, dim3(776), dim3(256), 0, stream,
                     Wa, Wih0, Whh0, Wih1, Whh1, Wv0, Wv1, Wt0, ws);
  hipLaunchKernelGGL(k_attn, dim3(512), dim3(256), 0, stream, obs, ws, ba);
  hipLaunchKernelGGL(k_gru, dim3(512), dim3(256), 0, stream,
                     ws, h0, bih0, bhh0, bv0, bt0, chosen,
                     h1, bih1, bhh1, bv1, out);
}